// Round 2
// baseline (26374.738 us; speedup 1.0000x reference)
//
#include <hip/hip_runtime.h>
#include <stdint.h>

typedef _Float16 f16;
typedef _Float16 f16x8 __attribute__((ext_vector_type(8)));
typedef float f32x4 __attribute__((ext_vector_type(4)));

#define TT 256
#define BB 256
#define II 128
#define HH 512
#define G4 2048   // 4*H
static constexpr size_t BH = (size_t)BB * HH;

// ---------------- helpers ----------------
__device__ __forceinline__ void gload_lds16(const void* g, void* l) {
  __builtin_amdgcn_global_load_lds(
      (const __attribute__((address_space(1))) unsigned int*)g,
      (__attribute__((address_space(3))) unsigned int*)l, 16, 0, 0);
}

__device__ __forceinline__ float fsig(float x) {
  x = fminf(fmaxf(x, -30.f), 30.f);
  float e = __builtin_amdgcn_exp2f(-1.44269504f * x);
  return __builtin_amdgcn_rcpf(1.f + e);
}
__device__ __forceinline__ float ftanh(float x) {
  x = fminf(fmaxf(x, -15.f), 15.f);
  float e = __builtin_amdgcn_exp2f(-2.88539008f * x);  // exp(-2x)
  return (1.f - e) * __builtin_amdgcn_rcpf(1.f + e);
}

// diagnostic: encode ws_size (MB) into the output if workspace is too small
__global__ void k_diag(float* out, float val) { out[0] = val; }

// ---------------- convert + transpose x chunk: [B][T][I] f32 -> [TC*B][I] f16 ----------------
__global__ __launch_bounds__(256) void k_conv_x(const float* __restrict__ x,
                                                f16* __restrict__ xhc, int t0) {
  int idx = blockIdx.x * 256 + threadIdx.x;  // unit = 8 floats
  int row = idx >> 4;                        // I/8 = 16 units per row
  int ii = (idx & 15) * 8;
  int tloc = row >> 8;                       // row = tloc*BB + b
  int b = row & 255;
  const float4* xs = (const float4*)(x + ((size_t)b * TT + (t0 + tloc)) * II + ii);
  float4 v0 = xs[0];
  float4 v1 = xs[1];
  f16x8 h;
  h[0] = (f16)v0.x; h[1] = (f16)v0.y; h[2] = (f16)v0.z; h[3] = (f16)v0.w;
  h[4] = (f16)v1.x; h[5] = (f16)v1.y; h[6] = (f16)v1.z; h[7] = (f16)v1.w;
  *(f16x8*)(xhc + (size_t)row * II + ii) = h;
}

// ---------------- convert weights to f16, sum biases ----------------
__global__ __launch_bounds__(256) void k_conv_w(
    const float* __restrict__ wih0, const float* __restrict__ whh0,
    const float* __restrict__ wih1, const float* __restrict__ whh1,
    const float* __restrict__ bih0, const float* __restrict__ bhh0,
    const float* __restrict__ bih1, const float* __restrict__ bhh1,
    f16* owih0, f16* owhh0, f16* owih1, f16* owhh1, float* ob0, float* ob1) {
  int i = blockIdx.x * 256 + threadIdx.x;
  if (i < G4 * II) owih0[i] = (f16)wih0[i];
  if (i < G4 * HH) {
    owhh0[i] = (f16)whh0[i];
    owih1[i] = (f16)wih1[i];
    owhh1[i] = (f16)whh1[i];
  }
  if (i < G4) {
    ob0[i] = bih0[i] + bhh0[i];
    ob1[i] = bih1[i] + bhh1[i];
  }
}

// ---------------- x_proj GEMM: C[m][n] = A[m][:] . Bw[n][:] + bias[n] ----------------
// A: [M][K] f16 row-major (m = tloc*256 + b), Bw: [2048][K] f16 row-major.
// Output written as xp[tloc][n][b] f16.
__device__ __forceinline__ f16x8 ldfrag32(const f16* S, int row, int ls) {
  int slot = ls ^ (row & 3);
  return *(const f16x8*)(S + row * 32 + slot * 8);
}

__global__ __launch_bounds__(256) void k_gemm(const f16* __restrict__ A,
                                              const f16* __restrict__ Bw,
                                              const float* __restrict__ bias,
                                              f16* __restrict__ xp, int K, int nmb) {
  __shared__ __align__(16) f16 As[128 * 32];
  __shared__ __align__(16) f16 Bs[128 * 32];
  int bx = blockIdx.x;
  int mblk = bx % nmb;
  int nblk = bx / nmb;
  int m0 = mblk * 128, n0 = nblk * 128;
  int tid = threadIdx.x;
  int l = tid & 63, w = tid >> 6;
  int lm = l & 15, ls = l >> 4;
  f32x4 acc[2][8] = {};

  for (int ks = 0; ks < K; ks += 32) {
#pragma unroll
    for (int q = 0; q < 2; ++q) {
      int r0 = (w * 2 + q) * 16;
      int row = r0 + (l >> 2);
      int g = (l & 3) ^ (row & 3);  // pre-swizzled global granule (m201 pattern)
      gload_lds16(A + (size_t)(m0 + row) * K + ks + g * 8, As + r0 * 32);
      gload_lds16(Bw + (size_t)(n0 + row) * K + ks + g * 8, Bs + r0 * 32);
    }
    __syncthreads();
    f16x8 a0 = ldfrag32(As, w * 32 + lm, ls);
    f16x8 a1 = ldfrag32(As, w * 32 + 16 + lm, ls);
#pragma unroll
    for (int nt = 0; nt < 8; ++nt) {
      f16x8 b = ldfrag32(Bs, nt * 16 + lm, ls);
      acc[0][nt] = __builtin_amdgcn_mfma_f32_16x16x32_f16(a0, b, acc[0][nt], 0, 0, 0);
      acc[1][nt] = __builtin_amdgcn_mfma_f32_16x16x32_f16(a1, b, acc[1][nt], 0, 0, 0);
    }
    __syncthreads();
  }
  // epilogue: xp[tloc][n][b] f16, 4 consecutive b packed per store
  unsigned short* xpo = (unsigned short*)xp;
#pragma unroll
  for (int mt = 0; mt < 2; ++mt) {
    int mbase = m0 + w * 32 + mt * 16 + 4 * ls;
    int t_ = mbase >> 8;
    int b_ = mbase & 255;
#pragma unroll
    for (int nt = 0; nt < 8; ++nt) {
      int n = n0 + nt * 16 + lm;
      float bv = bias[n];
      ushort4 pk;
      pk.x = __builtin_bit_cast(unsigned short, (f16)(acc[mt][nt][0] + bv));
      pk.y = __builtin_bit_cast(unsigned short, (f16)(acc[mt][nt][1] + bv));
      pk.z = __builtin_bit_cast(unsigned short, (f16)(acc[mt][nt][2] + bv));
      pk.w = __builtin_bit_cast(unsigned short, (f16)(acc[mt][nt][3] + bv));
      *(ushort4*)(xpo + ((size_t)t_ * G4 + n) * BB + b_) = pk;
    }
  }
}

// ---------------- persistent recurrent kernel (one time-chunk of nsteps) ----------------
// 256 blocks = 16 batch-groups (grp = bx&15, 16 rows each) x 16 col-slices
// (slice = bx>>4, 32 h-cols / 128 gate-cols each). W_hh slice lives in VGPRs.
__global__ __launch_bounds__(256, 1) void k_rec(
    const f16* __restrict__ xp, const f16* __restrict__ Whh,
    f16* __restrict__ hbase, const f16* __restrict__ hprev,
    float* __restrict__ cws, uint32_t* __restrict__ cnt,
    int t0, int nsteps, int ringmode) {
  __shared__ __align__(16) f16 hs[16 * 512];   // 16 KB, XOR-swizzled granules
  __shared__ __align__(16) float gs[128 * 20]; // gate preacts, padded rows

  int tid = threadIdx.x;
  int l = tid & 63, w = tid >> 6;  // w = gate chunk (i,f,g,o)
  int lm = l & 15, ls = l >> 4;
  int bx = blockIdx.x;
  int grp = bx & 15, slice = bx >> 4;
  int j0 = slice * 32;
  int brow0 = grp * 16;
  uint32_t* mycnt = cnt + grp * 256;  // indexed by GLOBAL t

  // preload W_hh fragments: 2 n-tiles x 16 k-steps, 8 f16 each -> 128 VGPRs
  f16x8 wf0[16], wf1[16];
#pragma unroll
  for (int kk = 0; kk < 16; ++kk) {
    wf0[kk] = *(const f16x8*)(Whh + (size_t)(w * 512 + j0 + lm) * HH + kk * 32 + ls * 8);
    wf1[kk] = *(const f16x8*)(Whh + (size_t)(w * 512 + j0 + 16 + lm) * HH + kk * 32 + ls * 8);
  }

  int eb = tid & 15;  // local batch row for elementwise
  int ej = tid >> 4;  // first local j
  int bglob = brow0 + eb;
  float cs0 = 0.f, cs1 = 0.f;
  if (t0 > 0) {  // restore carried cell state
    cs0 = cws[(size_t)bglob * HH + j0 + ej];
    cs1 = cws[(size_t)bglob * HH + j0 + 16 + ej];
  }
  const unsigned short* xpu = (const unsigned short*)xp;

#pragma unroll 1
  for (int tl = 0; tl < nsteps; ++tl) {
    int tg = t0 + tl;
    // prefetch xp gate biases for this step (independent of recurrence)
    unsigned short xpv[8];
#pragma unroll
    for (int c = 0; c < 4; ++c) {
      size_t base = ((size_t)tl * G4 + c * 512 + j0) * BB + bglob;
      xpv[c * 2]     = xpu[base + (size_t)ej * BB];
      xpv[c * 2 + 1] = xpu[base + (size_t)(ej + 16) * BB];
    }

    f32x4 acc0 = {0.f, 0.f, 0.f, 0.f}, acc1 = {0.f, 0.f, 0.f, 0.f};
    if (tg > 0) {
      if (tid == 0) {
        int guard = 0;
        while (__hip_atomic_load(&mycnt[tg - 1], __ATOMIC_RELAXED,
                                 __HIP_MEMORY_SCOPE_AGENT) < 16u) {
          __builtin_amdgcn_s_sleep(1);
          if (++guard > 200000) break;  // deadlock safety net
        }
      }
      __syncthreads();
      __threadfence();  // acquire: invalidate stale cache lines
      const f16* hin = (tl == 0)
                           ? hprev
                           : (ringmode ? hbase + (size_t)((tg - 1) & 1) * BH
                                       : hbase + (size_t)(tl - 1) * BH);
      // stage h_prev[16][512] -> swizzled LDS
      int srow = tid >> 4;
      const f16* gsrc = hin + (size_t)(brow0 + srow) * HH + (tid & 15) * 32;
      uint4 v0 = ((const uint4*)gsrc)[0];
      uint4 v1 = ((const uint4*)gsrc)[1];
      uint4 v2 = ((const uint4*)gsrc)[2];
      uint4 v3 = ((const uint4*)gsrc)[3];
      uint4* hsp = (uint4*)hs;
      int k16b = (tid & 15) * 4;
      hsp[srow * 64 + ((k16b + 0) ^ (srow & 7))] = v0;
      hsp[srow * 64 + ((k16b + 1) ^ (srow & 7))] = v1;
      hsp[srow * 64 + ((k16b + 2) ^ (srow & 7))] = v2;
      hsp[srow * 64 + ((k16b + 3) ^ (srow & 7))] = v3;
      __syncthreads();
#pragma unroll
      for (int kk = 0; kk < 16; ++kk) {
        int slot = (kk * 4 + ls) ^ (lm & 7);
        f16x8 a = *(const f16x8*)((const f16*)hs + lm * 512 + slot * 8);
        acc0 = __builtin_amdgcn_mfma_f32_16x16x32_f16(a, wf0[kk], acc0, 0, 0, 0);
        acc1 = __builtin_amdgcn_mfma_f32_16x16x32_f16(a, wf1[kk], acc1, 0, 0, 0);
      }
    }
    // gates -> LDS: gs[(chunk*32 + jloc)*20 + b]
    *(f32x4*)(gs + ((w * 32 + lm) * 20 + 4 * ls)) = acc0;
    *(f32x4*)(gs + ((w * 32 + 16 + lm) * 20 + 4 * ls)) = acc1;
    __syncthreads();

    // elementwise LSTM cell for (eb, ej) and (eb, ej+16)
    f16* hout = ringmode ? hbase + (size_t)(tg & 1) * BH
                         : hbase + (size_t)tl * BH;
    float hval[2];
#pragma unroll
    for (int s = 0; s < 2; ++s) {
      int jl = ej + s * 16;
      float pi = gs[(0 * 32 + jl) * 20 + eb] + (float)__builtin_bit_cast(f16, xpv[0 * 2 + s]);
      float pf = gs[(1 * 32 + jl) * 20 + eb] + (float)__builtin_bit_cast(f16, xpv[1 * 2 + s]);
      float pg = gs[(2 * 32 + jl) * 20 + eb] + (float)__builtin_bit_cast(f16, xpv[2 * 2 + s]);
      float po = gs[(3 * 32 + jl) * 20 + eb] + (float)__builtin_bit_cast(f16, xpv[3 * 2 + s]);
      float ig = fsig(pi), fg = fsig(pf), gg = ftanh(pg), og = fsig(po);
      float& cs = s ? cs1 : cs0;
      cs = fg * cs + ig * gg;
      hval[s] = og * ftanh(cs);
    }
    hout[(size_t)bglob * HH + j0 + ej] = (f16)hval[0];
    hout[(size_t)bglob * HH + j0 + 16 + ej] = (f16)hval[1];

    __threadfence();  // release: push h to coherent point
    __syncthreads();
    if (tid == 0)
      __hip_atomic_fetch_add(&mycnt[tg], 1u, __ATOMIC_RELEASE, __HIP_MEMORY_SCOPE_AGENT);
  }
  // persist cell state for next chunk
  cws[(size_t)bglob * HH + j0 + ej] = cs0;
  cws[(size_t)bglob * HH + j0 + 16 + ej] = cs1;
}

// ---------------- FC head: out[b] = h2_last[b][:] . fcw + fcb ----------------
__global__ __launch_bounds__(64) void k_fc(const f16* __restrict__ h2,
                                           const float* __restrict__ fcw,
                                           const float* __restrict__ fcb,
                                           float* __restrict__ out) {
  int b = blockIdx.x;
  int l = threadIdx.x;
  f16x8 hv = *(const f16x8*)(h2 + (size_t)b * HH + l * 8);
  float4 w0 = ((const float4*)fcw)[l * 2];
  float4 w1 = ((const float4*)fcw)[l * 2 + 1];
  float s = (float)hv[0] * w0.x + (float)hv[1] * w0.y + (float)hv[2] * w0.z +
            (float)hv[3] * w0.w + (float)hv[4] * w1.x + (float)hv[5] * w1.y +
            (float)hv[6] * w1.z + (float)hv[7] * w1.w;
#pragma unroll
  for (int off = 32; off > 0; off >>= 1) s += __shfl_down(s, off);
  if (l == 0) out[b] = s + fcb[0];
}

// ---------------- launch ----------------
extern "C" void kernel_launch(void* const* d_in, const int* in_sizes, int n_in,
                              void* d_out, int out_size, void* d_ws, size_t ws_size,
                              hipStream_t stream) {
  (void)in_sizes; (void)n_in; (void)out_size;

  const float* x    = (const float*)d_in[0];
  const float* wih0 = (const float*)d_in[1];
  const float* whh0 = (const float*)d_in[2];
  const float* bih0 = (const float*)d_in[3];
  const float* bhh0 = (const float*)d_in[4];
  const float* wih1 = (const float*)d_in[5];
  const float* whh1 = (const float*)d_in[6];
  const float* bih1 = (const float*)d_in[7];
  const float* bhh1 = (const float*)d_in[8];
  const float* fcw  = (const float*)d_in[9];
  const float* fcb  = (const float*)d_in[10];

  // fixed-size region
  const size_t SZ_WIH0 = (size_t)G4 * II * 2;
  const size_t SZ_WHH  = (size_t)G4 * HH * 2;
  const size_t SZ_B    = (size_t)G4 * 4;
  const size_t SZ_RING = 2 * BH * 2;
  const size_t SZ_C    = BH * 4;
  const size_t SZ_CNT  = (size_t)2 * 16 * 256 * 4;
  const size_t FIXED   = SZ_WIH0 + 3 * SZ_WHH + 2 * SZ_B + SZ_RING + 2 * SZ_C + SZ_CNT;

  // pick largest time-chunk TC that fits
  int TC = 0;
  const int cand[6] = {256, 128, 64, 32, 16, 8};
  for (int i = 0; i < 6; ++i) {
    int tc = cand[i];
    size_t need = (size_t)tc * G4 * BB * 2   // xp chunk
                + (size_t)tc * BB * HH * 2   // h1 chunk
                + (size_t)tc * BB * II * 2   // xh chunk
                + FIXED;
    if (need <= ws_size) { TC = tc; break; }
  }
  if (TC == 0) {  // encode ws_size (MB) into output for diagnosis
    k_diag<<<1, 1, 0, stream>>>((float*)d_out, (float)(ws_size >> 20));
    return;
  }

  char* ws = (char*)d_ws;
  size_t off = 0;
  f16* xp   = (f16*)(ws + off); off += (size_t)TC * G4 * BB * 2;
  f16* h1c  = (f16*)(ws + off); off += (size_t)TC * BB * HH * 2;
  f16* xhc  = (f16*)(ws + off); off += (size_t)TC * BB * II * 2;
  f16* cwih0 = (f16*)(ws + off); off += SZ_WIH0;
  f16* cwhh0 = (f16*)(ws + off); off += SZ_WHH;
  f16* cwih1 = (f16*)(ws + off); off += SZ_WHH;
  f16* cwhh1 = (f16*)(ws + off); off += SZ_WHH;
  float* b0 = (float*)(ws + off); off += SZ_B;
  float* b1 = (float*)(ws + off); off += SZ_B;
  f16* ring = (f16*)(ws + off); off += SZ_RING;
  float* cws0 = (float*)(ws + off); off += SZ_C;
  float* cws1 = (float*)(ws + off); off += SZ_C;
  uint32_t* cnt = (uint32_t*)(ws + off); off += SZ_CNT;

  hipMemsetAsync(cnt, 0, SZ_CNT, stream);
  k_conv_w<<<4096, 256, 0, stream>>>(wih0, whh0, wih1, whh1, bih0, bhh0, bih1, bhh1,
                                     cwih0, cwhh0, cwih1, cwhh1, b0, b1);

  uint32_t* cnt0 = cnt;
  uint32_t* cnt1 = cnt + 16 * 256;
  int nchunk = TT / TC;
  int nmb = TC * 2;  // (TC*256)/128 m-blocks
  for (int c = 0; c < nchunk; ++c) {
    int t0 = c * TC;
    k_conv_x<<<TC * 16, 256, 0, stream>>>(x, xhc, t0);
    // layer 0
    k_gemm<<<nmb * 16, 256, 0, stream>>>(xhc, cwih0, b0, xp, II, nmb);
    k_rec<<<256, 256, 0, stream>>>(xp, cwhh0, h1c, h1c + (size_t)(TC - 1) * BH,
                                   cws0, cnt0, t0, TC, 0);
    // layer 1
    k_gemm<<<nmb * 16, 256, 0, stream>>>(h1c, cwih1, b1, xp, HH, nmb);
    k_rec<<<256, 256, 0, stream>>>(xp, cwhh1, ring, ring + (size_t)((t0 - 1) & 1) * BH,
                                   cws1, cnt1, t0, TC, 1);
  }
  // FC on h2[T-1] (ring slot (TT-1)&1 == 1)
  k_fc<<<256, 64, 0, stream>>>(ring + BH, fcw, fcb, (float*)d_out);
}

// Round 3
// 2203.664 us; speedup vs baseline: 11.9686x; 11.9686x over previous
//
#include <hip/hip_runtime.h>
#include <stdint.h>

typedef _Float16 f16;
typedef _Float16 f16x8 __attribute__((ext_vector_type(8)));
typedef float f32x4 __attribute__((ext_vector_type(4)));

#define TT 256
#define BB 256
#define II 128
#define HH 512
#define G4 2048   // 4*H
static constexpr size_t BH = (size_t)BB * HH;

// ---------------- helpers ----------------
__device__ __forceinline__ void gload_lds16(const void* g, void* l) {
  __builtin_amdgcn_global_load_lds(
      (const __attribute__((address_space(1))) unsigned int*)g,
      (__attribute__((address_space(3))) unsigned int*)l, 16, 0, 0);
}

// agent-coherent u64 access: global_load/store_dwordx2 with sc1 — bypasses
// the non-coherent L1/L2 and is served at the device coherence point (MALL).
// This replaces cache-wide __threadfence (buffer_inv/buffer_wbl2) entirely.
__device__ __forceinline__ uint64_t ld_agent_u64(const uint64_t* p) {
  return __hip_atomic_load(p, __ATOMIC_RELAXED, __HIP_MEMORY_SCOPE_AGENT);
}
__device__ __forceinline__ void st_agent_u64(uint64_t* p, uint64_t v) {
  __hip_atomic_store(p, v, __ATOMIC_RELAXED, __HIP_MEMORY_SCOPE_AGENT);
}
__device__ __forceinline__ uint4 mk4(uint64_t a, uint64_t b) {
  uint4 r;
  r.x = (uint32_t)a; r.y = (uint32_t)(a >> 32);
  r.z = (uint32_t)b; r.w = (uint32_t)(b >> 32);
  return r;
}

__device__ __forceinline__ float fsig(float x) {
  x = fminf(fmaxf(x, -30.f), 30.f);
  float e = __builtin_amdgcn_exp2f(-1.44269504f * x);
  return __builtin_amdgcn_rcpf(1.f + e);
}
__device__ __forceinline__ float ftanh(float x) {
  x = fminf(fmaxf(x, -15.f), 15.f);
  float e = __builtin_amdgcn_exp2f(-2.88539008f * x);  // exp(-2x)
  return (1.f - e) * __builtin_amdgcn_rcpf(1.f + e);
}

// diagnostic: encode ws_size (MB) into the output if workspace is too small
__global__ void k_diag(float* out, float val) { out[0] = val; }

// ---------------- convert + transpose x chunk: [B][T][I] f32 -> [TC*B][I] f16 ----------------
__global__ __launch_bounds__(256) void k_conv_x(const float* __restrict__ x,
                                                f16* __restrict__ xhc, int t0) {
  int idx = blockIdx.x * 256 + threadIdx.x;  // unit = 8 floats
  int row = idx >> 4;                        // I/8 = 16 units per row
  int ii = (idx & 15) * 8;
  int tloc = row >> 8;                       // row = tloc*BB + b
  int b = row & 255;
  const float4* xs = (const float4*)(x + ((size_t)b * TT + (t0 + tloc)) * II + ii);
  float4 v0 = xs[0];
  float4 v1 = xs[1];
  f16x8 h;
  h[0] = (f16)v0.x; h[1] = (f16)v0.y; h[2] = (f16)v0.z; h[3] = (f16)v0.w;
  h[4] = (f16)v1.x; h[5] = (f16)v1.y; h[6] = (f16)v1.z; h[7] = (f16)v1.w;
  *(f16x8*)(xhc + (size_t)row * II + ii) = h;
}

// ---------------- convert weights to f16, sum biases ----------------
__global__ __launch_bounds__(256) void k_conv_w(
    const float* __restrict__ wih0, const float* __restrict__ whh0,
    const float* __restrict__ wih1, const float* __restrict__ whh1,
    const float* __restrict__ bih0, const float* __restrict__ bhh0,
    const float* __restrict__ bih1, const float* __restrict__ bhh1,
    f16* owih0, f16* owhh0, f16* owih1, f16* owhh1, float* ob0, float* ob1) {
  int i = blockIdx.x * 256 + threadIdx.x;
  if (i < G4 * II) owih0[i] = (f16)wih0[i];
  if (i < G4 * HH) {
    owhh0[i] = (f16)whh0[i];
    owih1[i] = (f16)wih1[i];
    owhh1[i] = (f16)whh1[i];
  }
  if (i < G4) {
    ob0[i] = bih0[i] + bhh0[i];
    ob1[i] = bih1[i] + bhh1[i];
  }
}

// ---------------- x_proj GEMM: C[m][n] = A[m][:] . Bw[n][:] + bias[n] ----------------
__device__ __forceinline__ f16x8 ldfrag32(const f16* S, int row, int ls) {
  int slot = ls ^ (row & 3);
  return *(const f16x8*)(S + row * 32 + slot * 8);
}

__global__ __launch_bounds__(256) void k_gemm(const f16* __restrict__ A,
                                              const f16* __restrict__ Bw,
                                              const float* __restrict__ bias,
                                              f16* __restrict__ xp, int K, int nmb) {
  __shared__ __align__(16) f16 As[128 * 32];
  __shared__ __align__(16) f16 Bs[128 * 32];
  int bx = blockIdx.x;
  int mblk = bx % nmb;
  int nblk = bx / nmb;
  int m0 = mblk * 128, n0 = nblk * 128;
  int tid = threadIdx.x;
  int l = tid & 63, w = tid >> 6;
  int lm = l & 15, ls = l >> 4;
  f32x4 acc[2][8] = {};

  for (int ks = 0; ks < K; ks += 32) {
#pragma unroll
    for (int q = 0; q < 2; ++q) {
      int r0 = (w * 2 + q) * 16;
      int row = r0 + (l >> 2);
      int g = (l & 3) ^ (row & 3);  // pre-swizzled global granule
      gload_lds16(A + (size_t)(m0 + row) * K + ks + g * 8, As + r0 * 32);
      gload_lds16(Bw + (size_t)(n0 + row) * K + ks + g * 8, Bs + r0 * 32);
    }
    __syncthreads();
    f16x8 a0 = ldfrag32(As, w * 32 + lm, ls);
    f16x8 a1 = ldfrag32(As, w * 32 + 16 + lm, ls);
#pragma unroll
    for (int nt = 0; nt < 8; ++nt) {
      f16x8 b = ldfrag32(Bs, nt * 16 + lm, ls);
      acc[0][nt] = __builtin_amdgcn_mfma_f32_16x16x32_f16(a0, b, acc[0][nt], 0, 0, 0);
      acc[1][nt] = __builtin_amdgcn_mfma_f32_16x16x32_f16(a1, b, acc[1][nt], 0, 0, 0);
    }
    __syncthreads();
  }
  unsigned short* xpo = (unsigned short*)xp;
#pragma unroll
  for (int mt = 0; mt < 2; ++mt) {
    int mbase = m0 + w * 32 + mt * 16 + 4 * ls;
    int t_ = mbase >> 8;
    int b_ = mbase & 255;
#pragma unroll
    for (int nt = 0; nt < 8; ++nt) {
      int n = n0 + nt * 16 + lm;
      float bv = bias[n];
      ushort4 pk;
      pk.x = __builtin_bit_cast(unsigned short, (f16)(acc[mt][nt][0] + bv));
      pk.y = __builtin_bit_cast(unsigned short, (f16)(acc[mt][nt][1] + bv));
      pk.z = __builtin_bit_cast(unsigned short, (f16)(acc[mt][nt][2] + bv));
      pk.w = __builtin_bit_cast(unsigned short, (f16)(acc[mt][nt][3] + bv));
      *(ushort4*)(xpo + ((size_t)t_ * G4 + n) * BB + b_) = pk;
    }
  }
}

// ---------------- persistent recurrent kernel (one time-chunk of nsteps) ----------------
// 256 blocks = 16 batch-groups (grp = bx&15, 16 rows each) x 16 col-slices
// (slice = bx>>4, 32 h-cols / 128 gate-cols each). W_hh slice lives in VGPRs.
// Cross-block handshake: sc1 (agent) u64 loads/stores for h + relaxed agent
// atomic counters. NO cache-wide fences.
__global__ __launch_bounds__(256, 1) void k_rec(
    const f16* __restrict__ xp, const f16* __restrict__ Whh,
    f16* __restrict__ hbase, const f16* __restrict__ hprev,
    float* __restrict__ cws, uint32_t* __restrict__ cnt,
    int t0, int nsteps, int ringmode) {
  __shared__ __align__(16) f16 hs[16 * 512];   // 16 KB, XOR-swizzled granules
  __shared__ __align__(16) float gs[128 * 20]; // gate preacts, padded rows
  __shared__ __align__(16) f16 ho[16 * 32];    // h-out coalescing stage

  int tid = threadIdx.x;
  int l = tid & 63, w = tid >> 6;  // w = gate chunk (i,f,g,o)
  int lm = l & 15, ls = l >> 4;
  int bx = blockIdx.x;
  int grp = bx & 15, slice = bx >> 4;
  int j0 = slice * 32;
  int brow0 = grp * 16;
  uint32_t* mycnt = cnt + grp * 256;  // indexed by GLOBAL t

  // preload W_hh fragments: 2 n-tiles x 16 k-steps, 8 f16 each -> 128 VGPRs
  f16x8 wf0[16], wf1[16];
#pragma unroll
  for (int kk = 0; kk < 16; ++kk) {
    wf0[kk] = *(const f16x8*)(Whh + (size_t)(w * 512 + j0 + lm) * HH + kk * 32 + ls * 8);
    wf1[kk] = *(const f16x8*)(Whh + (size_t)(w * 512 + j0 + 16 + lm) * HH + kk * 32 + ls * 8);
  }

  int eb = tid & 15;   // local batch row for elementwise
  int ej = tid >> 4;   // first local j
  int bglob = brow0 + eb;
  int srow = tid >> 4; // staging: row 0..15
  int sseg = tid & 15; // staging: 32-f16 segment within row
  int seb = tid >> 3;  // store: row (tid<128 -> 0..15)
  int sjq = tid & 7;   // store: u64 quad within 32-f16 row segment

  float cs0 = 0.f, cs1 = 0.f;
  if (t0 > 0) {  // restore carried cell state
    cs0 = cws[(size_t)bglob * HH + j0 + ej];
    cs1 = cws[(size_t)bglob * HH + j0 + 16 + ej];
  }
  const unsigned short* xpu = (const unsigned short*)xp;

#pragma unroll 1
  for (int tl = 0; tl < nsteps; ++tl) {
    int tg = t0 + tl;
    // prefetch xp gate biases for this step (overlaps the wait)
    unsigned short xpv[8];
#pragma unroll
    for (int c = 0; c < 4; ++c) {
      size_t base = ((size_t)tl * G4 + c * 512 + j0) * BB + bglob;
      xpv[c * 2]     = xpu[base + (size_t)ej * BB];
      xpv[c * 2 + 1] = xpu[base + (size_t)(ej + 16) * BB];
    }

    f32x4 acc0 = {0.f, 0.f, 0.f, 0.f}, acc1 = {0.f, 0.f, 0.f, 0.f};
    if (tg > 0) {
      // all lanes poll the same counter line (broadcast load, no barrier hop)
      int guard = 0;
      while (__hip_atomic_load(&mycnt[tg - 1], __ATOMIC_RELAXED,
                               __HIP_MEMORY_SCOPE_AGENT) < 16u) {
        if (++guard > 500000) break;  // deadlock safety net
      }
      asm volatile("" ::: "memory");  // compiler-only fence: no hoisting loads above poll
      const f16* hin = (tl == 0)
                           ? hprev
                           : (ringmode ? hbase + (size_t)((tg - 1) & 1) * BH
                                       : hbase + (size_t)(tl - 1) * BH);
      // stage h_prev[16][512] -> swizzled LDS via agent-coherent u64 loads
      const uint64_t* hsrc =
          (const uint64_t*)(hin + (size_t)(brow0 + srow) * HH + sseg * 32);
      uint64_t v[8];
#pragma unroll
      for (int q = 0; q < 8; ++q) v[q] = ld_agent_u64(hsrc + q);
      uint4* hsp = (uint4*)hs;
      int k16b = sseg * 4;
#pragma unroll
      for (int q = 0; q < 4; ++q)
        hsp[srow * 64 + ((k16b + q) ^ (srow & 7))] = mk4(v[2 * q], v[2 * q + 1]);
      __syncthreads();
#pragma unroll
      for (int kk = 0; kk < 16; ++kk) {
        int slot = (kk * 4 + ls) ^ (lm & 7);
        f16x8 a = *(const f16x8*)((const f16*)hs + lm * 512 + slot * 8);
        acc0 = __builtin_amdgcn_mfma_f32_16x16x32_f16(a, wf0[kk], acc0, 0, 0, 0);
        acc1 = __builtin_amdgcn_mfma_f32_16x16x32_f16(a, wf1[kk], acc1, 0, 0, 0);
      }
    }
    // gates -> LDS: gs[(chunk*32 + jloc)*20 + b]
    *(f32x4*)(gs + ((w * 32 + lm) * 20 + 4 * ls)) = acc0;
    *(f32x4*)(gs + ((w * 32 + 16 + lm) * 20 + 4 * ls)) = acc1;
    __syncthreads();

    // elementwise LSTM cell for (eb, ej) and (eb, ej+16)
    float hval[2];
#pragma unroll
    for (int s = 0; s < 2; ++s) {
      int jl = ej + s * 16;
      float pi = gs[(0 * 32 + jl) * 20 + eb] + (float)__builtin_bit_cast(f16, xpv[0 * 2 + s]);
      float pf = gs[(1 * 32 + jl) * 20 + eb] + (float)__builtin_bit_cast(f16, xpv[1 * 2 + s]);
      float pg = gs[(2 * 32 + jl) * 20 + eb] + (float)__builtin_bit_cast(f16, xpv[2 * 2 + s]);
      float po = gs[(3 * 32 + jl) * 20 + eb] + (float)__builtin_bit_cast(f16, xpv[3 * 2 + s]);
      float ig = fsig(pi), fg = fsig(pf), gg = ftanh(pg), og = fsig(po);
      float& cs = s ? cs1 : cs0;
      cs = fg * cs + ig * gg;
      hval[s] = og * ftanh(cs);
    }
    ho[eb * 32 + ej] = (f16)hval[0];
    ho[eb * 32 + 16 + ej] = (f16)hval[1];
    __syncthreads();  // ho visible; also orders gs reads vs next-iter writes

    // coalesced agent-coherent h store: 128 threads x u64 (4 f16 each)
    f16* hout = ringmode ? hbase + (size_t)(tg & 1) * BH
                         : hbase + (size_t)tl * BH;
    if (tid < 128) {
      uint64_t pv = *(const uint64_t*)(ho + seb * 32 + sjq * 4);
      st_agent_u64((uint64_t*)(hout + (size_t)(brow0 + seb) * HH + j0 + sjq * 4), pv);
    }
    asm volatile("s_waitcnt vmcnt(0)" ::: "memory");  // stores reached MALL
    __syncthreads();
    if (tid == 0)
      __hip_atomic_fetch_add(&mycnt[tg], 1u, __ATOMIC_RELAXED, __HIP_MEMORY_SCOPE_AGENT);
  }
  // persist cell state for next chunk
  cws[(size_t)bglob * HH + j0 + ej] = cs0;
  cws[(size_t)bglob * HH + j0 + 16 + ej] = cs1;
}

// ---------------- FC head: out[b] = h2_last[b][:] . fcw + fcb ----------------
__global__ __launch_bounds__(64) void k_fc(const f16* __restrict__ h2,
                                           const float* __restrict__ fcw,
                                           const float* __restrict__ fcb,
                                           float* __restrict__ out) {
  int b = blockIdx.x;
  int l = threadIdx.x;
  f16x8 hv = *(const f16x8*)(h2 + (size_t)b * HH + l * 8);
  float4 w0 = ((const float4*)fcw)[l * 2];
  float4 w1 = ((const float4*)fcw)[l * 2 + 1];
  float s = (float)hv[0] * w0.x + (float)hv[1] * w0.y + (float)hv[2] * w0.z +
            (float)hv[3] * w0.w + (float)hv[4] * w1.x + (float)hv[5] * w1.y +
            (float)hv[6] * w1.z + (float)hv[7] * w1.w;
#pragma unroll
  for (int off = 32; off > 0; off >>= 1) s += __shfl_down(s, off);
  if (l == 0) out[b] = s + fcb[0];
}

// ---------------- launch ----------------
extern "C" void kernel_launch(void* const* d_in, const int* in_sizes, int n_in,
                              void* d_out, int out_size, void* d_ws, size_t ws_size,
                              hipStream_t stream) {
  (void)in_sizes; (void)n_in; (void)out_size;

  const float* x    = (const float*)d_in[0];
  const float* wih0 = (const float*)d_in[1];
  const float* whh0 = (const float*)d_in[2];
  const float* bih0 = (const float*)d_in[3];
  const float* bhh0 = (const float*)d_in[4];
  const float* wih1 = (const float*)d_in[5];
  const float* whh1 = (const float*)d_in[6];
  const float* bih1 = (const float*)d_in[7];
  const float* bhh1 = (const float*)d_in[8];
  const float* fcw  = (const float*)d_in[9];
  const float* fcb  = (const float*)d_in[10];

  const size_t SZ_WIH0 = (size_t)G4 * II * 2;
  const size_t SZ_WHH  = (size_t)G4 * HH * 2;
  const size_t SZ_B    = (size_t)G4 * 4;
  const size_t SZ_RING = 2 * BH * 2;
  const size_t SZ_C    = BH * 4;
  const size_t SZ_CNT  = (size_t)2 * 16 * 256 * 4;
  const size_t FIXED   = SZ_WIH0 + 3 * SZ_WHH + 2 * SZ_B + SZ_RING + 2 * SZ_C + SZ_CNT;

  int TC = 0;
  const int cand[6] = {256, 128, 64, 32, 16, 8};
  for (int i = 0; i < 6; ++i) {
    int tc = cand[i];
    size_t need = (size_t)tc * G4 * BB * 2   // xp chunk
                + (size_t)tc * BB * HH * 2   // h1 chunk
                + (size_t)tc * BB * II * 2   // xh chunk
                + FIXED;
    if (need <= ws_size) { TC = tc; break; }
  }
  if (TC == 0) {
    k_diag<<<1, 1, 0, stream>>>((float*)d_out, (float)(ws_size >> 20));
    return;
  }

  char* ws = (char*)d_ws;
  size_t off = 0;
  f16* xp   = (f16*)(ws + off); off += (size_t)TC * G4 * BB * 2;
  f16* h1c  = (f16*)(ws + off); off += (size_t)TC * BB * HH * 2;
  f16* xhc  = (f16*)(ws + off); off += (size_t)TC * BB * II * 2;
  f16* cwih0 = (f16*)(ws + off); off += SZ_WIH0;
  f16* cwhh0 = (f16*)(ws + off); off += SZ_WHH;
  f16* cwih1 = (f16*)(ws + off); off += SZ_WHH;
  f16* cwhh1 = (f16*)(ws + off); off += SZ_WHH;
  float* b0 = (float*)(ws + off); off += SZ_B;
  float* b1 = (float*)(ws + off); off += SZ_B;
  f16* ring = (f16*)(ws + off); off += SZ_RING;
  float* cws0 = (float*)(ws + off); off += SZ_C;
  float* cws1 = (float*)(ws + off); off += SZ_C;
  uint32_t* cnt = (uint32_t*)(ws + off); off += SZ_CNT;

  hipMemsetAsync(cnt, 0, SZ_CNT, stream);
  k_conv_w<<<4096, 256, 0, stream>>>(wih0, whh0, wih1, whh1, bih0, bhh0, bih1, bhh1,
                                     cwih0, cwhh0, cwih1, cwhh1, b0, b1);

  uint32_t* cnt0 = cnt;
  uint32_t* cnt1 = cnt + 16 * 256;
  int nchunk = TT / TC;
  int nmb = TC * 2;  // (TC*256)/128 m-blocks
  for (int c = 0; c < nchunk; ++c) {
    int t0 = c * TC;
    k_conv_x<<<TC * 16, 256, 0, stream>>>(x, xhc, t0);
    // layer 0
    k_gemm<<<nmb * 16, 256, 0, stream>>>(xhc, cwih0, b0, xp, II, nmb);
    k_rec<<<256, 256, 0, stream>>>(xp, cwhh0, h1c, h1c + (size_t)(TC - 1) * BH,
                                   cws0, cnt0, t0, TC, 0);
    // layer 1
    k_gemm<<<nmb * 16, 256, 0, stream>>>(h1c, cwih1, b1, xp, HH, nmb);
    k_rec<<<256, 256, 0, stream>>>(xp, cwhh1, ring, ring + (size_t)((t0 - 1) & 1) * BH,
                                   cws1, cnt1, t0, TC, 1);
  }
  // FC on h2[T-1] (ring slot (TT-1)&1 == 1)
  k_fc<<<256, 64, 0, stream>>>(ring + BH, fcw, fcb, (float*)d_out);
}